// Round 1
// baseline (105.752 us; speedup 1.0000x reference)
//
#include <hip/hip_runtime.h>
#include <math.h>

#define NPTS 16384
#define HDIM 64
#define NBINS 32768
#define XLO -8.0f
#define INVW 2048.0f            // NBINS / (XHI - XLO) = 32768/16
#define EPSF 1e-8f
#define FMAX3 3.402823466e38f

// Monotone, consistent bin index (same fn used by hist/scatter => bin-major order
// is a valid coarse sort; clamp handles |x|>8 which is ~16-sigma impossible).
__device__ __forceinline__ int bin_of(float v) {
    int b = (int)((v - XLO) * INVW);
    return min(max(b, 0), NBINS - 1);
}

// keep-2-smallest insert (m1<=m2). m2 reads OLD m1 -> order matters.
__device__ __forceinline__ void ins2(float& m1, float& m2, float d) {
    m2 = __builtin_amdgcn_fmed3f(d, m1, m2);
    m1 = fminf(d, m1);
}

// K2: histogram. 16384 atomics over 32768 bins -> negligible contention.
__global__ __launch_bounds__(256) void hist_kernel(
    const float* __restrict__ x, unsigned* __restrict__ hist) {
    const int i = blockIdx.x * 256 + threadIdx.x;
    atomicAdd(&hist[bin_of(x[i])], 1u);
}

// K3: exclusive prefix over 32768 bins, single block of 1024 (32 bins/thread,
// register-staged, all-static indexing). Writes the scatter cursor array.
__global__ __launch_bounds__(1024) void prefix_kernel(
    const unsigned* __restrict__ hist, unsigned* __restrict__ cursor) {
    const int t = threadIdx.x;
    const int base = t * 32;
    unsigned c[32];
#pragma unroll
    for (int k = 0; k < 32; ++k) c[k] = hist[base + k];
    unsigned s = 0;
#pragma unroll
    for (int k = 0; k < 32; ++k) { unsigned v = c[k]; c[k] = s; s += v; }
    // wave-inclusive scan of thread totals
    unsigned inc = s;
    const int lane = t & 63;
#pragma unroll
    for (int o = 1; o < 64; o <<= 1) {
        unsigned n = __shfl_up(inc, o);
        if (lane >= o) inc += n;
    }
    __shared__ unsigned wsum[16];
    const int wv = t >> 6;
    if (lane == 63) wsum[wv] = inc;
    __syncthreads();
    unsigned woff = 0;
#pragma unroll
    for (int k = 0; k < 16; ++k) woff += (k < wv) ? wsum[k] : 0u;
    const unsigned excl = woff + inc - s;
#pragma unroll
    for (int k = 0; k < 32; ++k) cursor[base + k] = excl + c[k];
}

// K4: scatter values into bin-grouped order (order within bin arbitrary; K5 fixes).
__global__ __launch_bounds__(256) void scatter_kernel(
    const float* __restrict__ x, unsigned* __restrict__ cursor,
    float* __restrict__ vals) {
    const int i = blockIdx.x * 256 + threadIdx.x;
    const float v = x[i];
    const unsigned pos = atomicAdd(&cursor[bin_of(v)], 1u);
    vals[pos] = v;
}

// K5: sort within each bin. After scatter, cursor[b] == end-of-bin-b, so
// start = cursor[b-1]. lambda_max ~= 3.2 -> n<=16 covers P > 1 - 2e-4; the
// global insertion-sort fallback keeps it exact regardless.
__global__ __launch_bounds__(256) void binsort_kernel(
    const unsigned* __restrict__ cursor, float* __restrict__ vals) {
    const int b = blockIdx.x * 256 + threadIdx.x;
    const unsigned s = (b > 0) ? cursor[b - 1] : 0u;
    const unsigned e = cursor[b];
    const unsigned n = e - s;
    if (n < 2u) return;
    if (n <= 16u) {
        float r[16];
#pragma unroll
        for (int k = 0; k < 16; ++k)
            r[k] = (k < (int)n) ? vals[s + k] : FMAX3;  // pad reads stay inside ws
        // odd-even transposition network, fully static indices -> registers
#pragma unroll
        for (int rd = 0; rd < 16; ++rd) {
#pragma unroll
            for (int j = (rd & 1); j + 1 < 16; j += 2) {
                float lo = fminf(r[j], r[j + 1]);
                float hi = fmaxf(r[j], r[j + 1]);
                r[j] = lo; r[j + 1] = hi;
            }
        }
#pragma unroll
        for (int k = 0; k < 16; ++k)
            if (k < (int)n) vals[s + k] = r[k];
    } else {
        for (unsigned a = s + 1; a < e; ++a) {  // never-taken safety path
            float key = vals[a];
            unsigned j = a;
            while (j > s && vals[j - 1] > key) { vals[j] = vals[j - 1]; --j; }
            vals[j] = key;
        }
    }
}

// K6: density from sorted window +-2 (exact 2-NN in 1-D; dens enters output only
// as mean/max => multiset suffices, no index map back) fused with the proven
// MLP + analytic d2y/dx2 + reduction/ticket epilogue (unchanged from merge).
// Reference: knn = [EPS, d1+EPS, d2+EPS]; mean+EPS = (d1+d2)/3 + 2*EPS.
__global__ __launch_bounds__(64) void final_kernel(
    const float* __restrict__ x, const float* __restrict__ tg,
    const float* __restrict__ w1, const float* __restrict__ b1,
    const float* __restrict__ w2, const float* __restrict__ b2,
    const float* __restrict__ vals, float* __restrict__ acc,
    float* __restrict__ out) {
    const int t = threadIdx.x;        // block = one wave
    const int i = blockIdx.x * 64 + t;

    const float vp = vals[i];
    const float dm1 = (i >= 1) ? vp - vals[i - 1] : FMAX3;      // sorted -> >=0
    const float dm2 = (i >= 2) ? vp - vals[i - 2] : FMAX3;      // dm2 >= dm1
    const float dp1 = (i + 1 < NPTS) ? vals[i + 1] - vp : FMAX3;
    const float dp2 = (i + 2 < NPTS) ? vals[i + 2] - vp : FMAX3; // dp2 >= dp1
    // two smallest of {dm1,dm2,dp1,dp2} using per-side monotonicity
    const float m1 = fminf(dm1, dp1);
    const float s2 = (dm1 <= dp1) ? dm2 : dp2;
    const float m2 = fminf(fmaxf(dm1, dp1), s2);
    const float dens = 1.0f / ((m1 + m2) * (1.0f / 3.0f) + 2.0f * EPSF);

    const float xi = x[i];
    float y = b2[0];
    float d2a = 0.0f;
#pragma unroll 8
    for (int j = 0; j < HDIM; ++j) {
        float a1 = w1[j], bb = b1[j], a2 = w2[j];   // uniform -> scalar loads
        float u = fmaf(xi, a1, bb);
        float e = __expf(2.0f * u);
        float r = __builtin_amdgcn_rcpf(e + 1.0f);
        float tt = fmaf(-2.0f, r, 1.0f);            // tanh(u)
        y = fmaf(a2, tt, y);
        float g = 2.0f * tt * fmaf(tt, tt, -1.0f);  // -2 t (1 - t^2)
        d2a = fmaf(a2 * a1 * a1, g, d2a);
    }
    float diff = y - tg[i];
    float rs_mse = diff * diff;
    float rs_d2 = d2a * d2a;
    float rs_dn = dens, rmx = dens;
    for (int o = 32; o > 0; o >>= 1) {
        rs_mse += __shfl_down(rs_mse, o);
        rs_d2 += __shfl_down(rs_d2, o);
        rs_dn += __shfl_down(rs_dn, o);
        rmx = fmaxf(rmx, __shfl_down(rmx, o));
    }
    if (t == 0) {
        atomicAdd(&acc[0], rs_mse);
        atomicAdd(&acc[1], rs_d2);
        atomicAdd(&acc[2], rs_dn);
        atomicMax((unsigned int*)&acc[3], __float_as_uint(rmx));  // dens>0: uint order == float order
        __threadfence();
        unsigned int ticket = atomicAdd((unsigned int*)&acc[4], 1u);
        if (ticket == (NPTS / 64) - 1) {
            float s_mse = atomicAdd(&acc[0], 0.0f);
            float s_d2 = atomicAdd(&acc[1], 0.0f);
            float s_dn = atomicAdd(&acc[2], 0.0f);
            float dmax = __uint_as_float(atomicMax((unsigned int*)&acc[3], 0u));
            float mse = s_mse * (1.0f / NPTS);
            float md2 = s_d2 * (1.0f / NPTS);
            float mean_density = (s_dn * (1.0f / NPTS)) / (dmax + EPSF);
            float penalty = 0.01f * (1.0f + 0.1f * mean_density) * md2;
            out[0] = mse + penalty;
            out[1] = mse;
            out[2] = penalty;
        }
    }
}

extern "C" void kernel_launch(void* const* d_in, const int* in_sizes, int n_in,
                              void* d_out, int out_size, void* d_ws, size_t ws_size,
                              hipStream_t stream) {
    const float* x = (const float*)d_in[0];
    const float* tg = (const float*)d_in[1];
    const float* w1 = (const float*)d_in[2];
    const float* b1 = (const float*)d_in[3];
    const float* w2 = (const float*)d_in[4];
    const float* b2 = (const float*)d_in[5];
    float* out = (float*)d_out;
    float* wsf = (float*)d_ws;

    float* acc = wsf;                                  // [0..7]: sums, max, ticket
    unsigned* hist = (unsigned*)(wsf + 8);             // 32768 u32
    unsigned* cursor = hist + NBINS;                   // 32768 u32 (prefix -> scatter ends)
    float* vals = (float*)(cursor + NBINS);            // 16384 f32, sorted

    // zero acc + hist in one memset node (graph-capturable)
    hipMemsetAsync(d_ws, 0, (8 + NBINS) * sizeof(float), stream);
    hipLaunchKernelGGL(hist_kernel, dim3(NPTS / 256), dim3(256), 0, stream, x, hist);
    hipLaunchKernelGGL(prefix_kernel, dim3(1), dim3(1024), 0, stream, hist, cursor);
    hipLaunchKernelGGL(scatter_kernel, dim3(NPTS / 256), dim3(256), 0, stream, x, cursor, vals);
    hipLaunchKernelGGL(binsort_kernel, dim3(NBINS / 256), dim3(256), 0, stream, cursor, vals);
    hipLaunchKernelGGL(final_kernel, dim3(NPTS / 64), dim3(64), 0, stream,
                       x, tg, w1, b1, w2, b2, vals, acc, out);
}